// Round 9
// baseline (4484.601 us; speedup 1.0000x reference)
//
#include <hip/hip_runtime.h>
#include <cstddef>
#include <cstdint>

// Round 8: 64x128 tiles, 4 blocks/CU (16 waves/CU) — double per-CU memory
// concurrency (r2 evidence: fill rate scales with resident blocks/CU).
// B direct-to-register (ring of 3), A via LDS (3 x 4KB, depth 2), uniform
// vmcnt(5) ledger. Nontemporal hints reverted (r7: pure regression).

namespace {

typedef short s8v __attribute__((ext_vector_type(8)));
typedef float f4v __attribute__((ext_vector_type(4)));
typedef unsigned short ushort_t;

__device__ inline unsigned short f2bf(float f) {
    union { float f; unsigned u; } v; v.f = f;
    unsigned r = v.u + 0x7fff + ((v.u >> 16) & 1);
    return (unsigned short)(r >> 16);
}
__device__ inline float bf2f(ushort_t u) {
    union { unsigned u; float f; } v; v.u = ((unsigned)u) << 16; return v.f;
}
__device__ inline float sigm_f(float x) { return 1.f / (1.f + __expf(-x)); }
__device__ inline float tanh_f(float x) {
    const float e = __expf(2.f * fabsf(x));
    return copysignf(1.f - 2.f / (e + 1.f), x);
}

#define GLOAD_LDS(gp, lp)                                              \
    __builtin_amdgcn_global_load_lds(                                  \
        (const __attribute__((address_space(1))) void*)(gp),           \
        (__attribute__((address_space(3))) void*)(lp), 16, 0, 0)

// ---------------------------------------------------------------------------
// GEMM core: 64x128 tile, BK=32, 4 waves (2x2, wave-tile 32x64), acc[2][4].
// A row-major bf16 [M][K] via LDS (4KB/tile, ring of 3, depth 2), 2-way-max
// chunk swizzle (phys chunk = logical ^ ((row>>1)&3), pre-swizzled source).
// B direct-to-register from fragment-major packed weights, ring of 3.
// Ledger: prologue B0,A0,B1,A1 (6 loads). iter t: vmcnt(5) retires B(t),A(t);
// barrier; issue A(t+2),B(t+2) (outstanding 10 during compute).
// ---------------------------------------------------------------------------
__device__ __forceinline__ void gemm_core(
    const ushort_t* __restrict__ A1a, const ushort_t* __restrict__ A1b,
    int lda1, int K1, const ushort_t* __restrict__ W1,
    const ushort_t* __restrict__ A2, int lda2, int K2,
    const ushort_t* __restrict__ W2,
    int bm, int bn, ushort_t* lds, f4v acc[2][4])
{
    const int tid = threadIdx.x;
    const int wid = tid >> 6;
    const int lane = tid & 63;
    const int wr = wid >> 1, wc = wid & 1;
    const int lrow = lane & 15, lkg = lane >> 4;

    const int n1 = K1 >> 5;
    const int n2 = (W2 != nullptr) ? (K2 >> 5) : 0;
    const int nt = n1 + n2;

    // ---- A staging: wave wid covers rows [wid*16, +16), lane -> row lane>>2,
    // chunk lane&3; source chunk pre-swizzled; LDS dest linear (lane*16B). ----
    const int srow = wid * 16 + (lane >> 2);
    const int ssrc = (((lane & 3) ^ ((srow >> 1) & 3)) << 3);  // elems

    auto arow = [&](const ushort_t* Aa, const ushort_t* Ab, int lda,
                    int r) -> const ushort_t* {
        return (Ab != nullptr && r >= 512) ? Ab + (size_t)(r - 512) * lda
                                           : Aa + (size_t)r * lda;
    };
    const ushort_t* pA1 = arow(A1a, A1b, lda1, bm + srow) + ssrc;
    const ushort_t* pA2 = nullptr;
    if (n2 > 0) pA2 = A2 + (size_t)(bm + srow) * lda2 + ssrc;

    auto stageA = [&](int idx, int buf) {
        const ushort_t* p;
        if (idx < n1) p = pA1 + (idx << 5);
        else          p = pA2 + ((idx - n1) << 5);
        GLOAD_LDS(p, lds + buf * 2048 + wid * 512);
    };

    // ---- B packed bases: wave's 4 fragments at nb0 = bn/16 + wc*4 ----
    const int nb0 = (bn >> 4) + wc * 4;
    const ushort_t* W1l = W1 + (size_t)nb0 * n1 * 512 + lane * 8;
    const ushort_t* W2l = (n2 > 0) ? (W2 + (size_t)nb0 * n2 * 512 + lane * 8) : nullptr;

    auto loadB = [&](int t, s8v (&b)[4]) {
        const ushort_t* base; int kb, KB;
        if (t < n1) { base = W1l; kb = t; KB = n1; }
        else        { base = W2l; kb = t - n1; KB = n2; }
#pragma unroll
        for (int n = 0; n < 4; ++n)
            b[n] = *(const s8v*)(base + ((size_t)(n * KB + kb) << 9));
    };

    // ---- A fragment read offsets (swizzled), loop-invariant ----
    int aoff[2];
#pragma unroll
    for (int m = 0; m < 2; ++m) {
        const int r = wr * 32 + m * 16 + lrow;
        aoff[m] = r * 32 + ((lkg ^ ((r >> 1) & 3)) << 3);
    }

    s8v b0[4], b1[4], b2[4];
    loadB(0, b0);
    stageA(0, 0);
    loadB(1, b1);
    stageA(1, 1);

    int cbuf = 0, sbuf = 2;
    auto iter = [&](int t, s8v (&bcur)[4], s8v (&bpre)[4]) {
        if (t + 1 < nt) asm volatile("s_waitcnt vmcnt(5)" ::: "memory");
        else            asm volatile("s_waitcnt vmcnt(0)" ::: "memory");
        __builtin_amdgcn_s_barrier();
        __builtin_amdgcn_sched_barrier(0);
        if (t + 2 < nt) {
            stageA(t + 2, sbuf);
            loadB(t + 2, bpre);
            sbuf = (sbuf == 2) ? 0 : sbuf + 1;
        }
        const ushort_t* L = lds + cbuf * 2048;
        s8v a[2];
#pragma unroll
        for (int m = 0; m < 2; ++m) a[m] = *(const s8v*)(L + aoff[m]);
        __builtin_amdgcn_s_setprio(1);
#pragma unroll
        for (int m = 0; m < 2; ++m)
#pragma unroll
            for (int n = 0; n < 4; ++n)
                acc[m][n] = __builtin_amdgcn_mfma_f32_16x16x32_bf16(
                    a[m], bcur[n], acc[m][n], 0, 0, 0);
        __builtin_amdgcn_s_setprio(0);
        cbuf = (cbuf == 2) ? 0 : cbuf + 1;
    };

    int t = 0;
    while (true) {
        iter(t, b0, b2); if (++t == nt) break;
        iter(t, b1, b0); if (++t == nt) break;
        iter(t, b2, b1); if (++t == nt) break;
    }
}

// ---------------------------------------------------------------------------
// Plain GEMM: C = act(A@W^T + bias). M%64==0, N%128==0, K%32==0.
// ---------------------------------------------------------------------------
template <int ACT>  // 0 none, 1 tanh
__global__ __launch_bounds__(256, 4) void plain_gemm(
    const ushort_t* __restrict__ A, int lda, int K,
    const ushort_t* __restrict__ W,
    const float* __restrict__ bias, int bias_n,
    float* __restrict__ C, ushort_t* __restrict__ Cbf, int N)
{
    __shared__ __align__(16) ushort_t lds[3 * 2048];
    const int bm = blockIdx.x * 64, bn = blockIdx.y * 128;
    f4v acc[2][4] = {};
    gemm_core(A, nullptr, lda, K, W, nullptr, 0, 0, nullptr, bm, bn, lds, acc);

    const int tid = threadIdx.x, wid = tid >> 6, lane = tid & 63;
    const int wr = wid >> 1, wc = wid & 1, lrow = lane & 15, lkg = lane >> 4;
#pragma unroll
    for (int m = 0; m < 2; ++m) {
        const int row0 = bm + wr * 32 + m * 16 + lkg * 4;
#pragma unroll
        for (int n = 0; n < 4; ++n) {
            const int col = bn + wc * 64 + n * 16 + lrow;
            const float bv = (bias != nullptr && col < bias_n) ? bias[col] : 0.f;
#pragma unroll
            for (int r = 0; r < 4; ++r) {
                float v = acc[m][n][r] + bv;
                if (ACT == 1) v = tanh_f(v);
                const size_t o = (size_t)(row0 + r) * N + col;
                if (C != nullptr) C[o] = v;
                if (Cbf != nullptr) Cbf[o] = f2bf(v);
            }
        }
    }
}

// ---------------------------------------------------------------------------
// Fused LSTM step. Weights gate-interleaved: col' = (j>>4)*64 + g*16 + (j&15).
// ---------------------------------------------------------------------------
struct Prob {
    const ushort_t* A1a; const ushort_t* A1b; int lda1; int K1;
    const ushort_t* B1t;   // packed frag-major
    const ushort_t* A2; int lda2; int K2; const ushort_t* B2t;  // packed
    const ushort_t* Dbf;   // bf16 [M][4096] pre-gates (incl. bias), or null
    const float* bias;     // fp32 [4096] permuted combined bias, or null
    float* cst;            // fp32 [M][1024] cell state (in/out)
    ushort_t* hout;        // bf16 [M][1024] new hidden
    ushort_t* hs;          // optional extra hidden dest
    int step_s;            // -1: identity; >=0: decoder hs mapping
};

__global__ __launch_bounds__(256, 4) void lstm_step(Prob PA, int nxa, Prob PB,
                                                    int mshift)
{
    __shared__ __align__(16) ushort_t lds[3 * 2048];
    const int nblk = gridDim.x;
    const int wg = blockIdx.x;
    const int swz = (wg & 7) * (nblk >> 3) + (wg >> 3);
    const int nmb = 1 << mshift;
    const int nb = swz >> mshift;
    const int mb = swz & (nmb - 1);

    const bool isA = mb < nxa;
    const Prob& P = isA ? PA : PB;
    const int bm = (isA ? mb : mb - nxa) * 64;
    const int bn = nb * 128;

    f4v acc[2][4] = {};
    gemm_core(P.A1a, P.A1b, P.lda1, P.K1, P.B1t,
              P.A2, P.lda2, P.K2, P.B2t, bm, bn, lds, acc);

    const int tid = threadIdx.x, wid = tid >> 6, lane = tid & 63;
    const int wr = wid >> 1, wc = wid & 1, lrow = lane & 15, lkg = lane >> 4;
    const int colbase = bn + wc * 64;           // 64-aligned
    const int jb = (colbase >> 6) * 16 + lrow;  // hidden-unit index

#pragma unroll
    for (int m = 0; m < 2; ++m) {
        const int row0 = bm + wr * 32 + m * 16 + lkg * 4;
#pragma unroll
        for (int r = 0; r < 4; ++r) {
            const int row = row0 + r;
            float g0 = acc[m][0][r], g1 = acc[m][1][r];
            float g2 = acc[m][2][r], g3 = acc[m][3][r];
            if (P.Dbf != nullptr) {
                const ushort_t* d = P.Dbf + (size_t)row * 4096 + colbase + lrow;
                g0 += bf2f(d[0]); g1 += bf2f(d[16]);
                g2 += bf2f(d[32]); g3 += bf2f(d[48]);
            }
            if (P.bias != nullptr) {
                const float* b = P.bias + colbase + lrow;
                g0 += b[0]; g1 += b[16]; g2 += b[32]; g3 += b[48];
            }
            const size_t ci = (size_t)row * 1024 + jb;
            const float cn = fmaf(sigm_f(g1), P.cst[ci], sigm_f(g0) * tanh_f(g2));
            const float hn = sigm_f(g3) * tanh_f(cn);
            P.cst[ci] = cn;
            const ushort_t hb = f2bf(hn);
            P.hout[ci] = hb;
            if (P.hs != nullptr) {
                size_t d;
                if (P.step_s >= 0) {
                    const int u = row >> 9, b = row & 511;
                    d = ((size_t)((u * 16 + P.step_s) * 512 + b) << 10) + jb;
                } else {
                    d = ci;
                }
                P.hs[d] = hb;
            }
        }
    }
}

// ---------------------------------------------------------------------------
// Weight pack: fp32 W[K][N] -> fragment-major bf16 (see round 6).
// ---------------------------------------------------------------------------
template <int PERM>
__global__ __launch_bounds__(256) void pack_frag_bf16(
    const float* __restrict__ in, ushort_t* __restrict__ out,
    int K, int N, int Kp, int Np)
{
    __shared__ float tile[32][33];
    const int kb = blockIdx.x;
    const int np0 = blockIdx.y * 32;
    const int k0 = kb * 32;
    const int tx = threadIdx.x & 31;
    const int ty = threadIdx.x >> 5;  // 0..7
#pragma unroll
    for (int q = 0; q < 4; ++q) {
        const int k = k0 + ty + 8 * q;
        const int np = np0 + tx;
        int n;
        if (PERM) n = ((np >> 4) & 3) * 1024 + (np >> 6) * 16 + (np & 15);
        else      n = np;
        tile[ty + 8 * q][tx] = (k < K && n < N) ? in[(size_t)k * N + n] : 0.f;
    }
    __syncthreads();
    const int t = threadIdx.x;
    const int rec = t >> 7;           // 0..1
    const int lane = (t >> 1) & 63;
    const int half = t & 1;
    const size_t grec = (size_t)(np0 / 16 + rec) * (Kp / 32) + kb;
    const int kl = (lane >> 4) * 8 + half * 4;
    const int nl = rec * 16 + (lane & 15);
    ushort4 v;
    v.x = f2bf(tile[kl + 0][nl]);
    v.y = f2bf(tile[kl + 1][nl]);
    v.z = f2bf(tile[kl + 2][nl]);
    v.w = f2bf(tile[kl + 3][nl]);
    *(ushort4*)(out + (grec * 64 + lane) * 8 + half * 4) = v;
}

__global__ void convert_pad_bf16(const float* __restrict__ in,
                                 ushort_t* __restrict__ out,
                                 int K, int Kp, int total)
{
    const int idx = blockIdx.x * 256 + threadIdx.x;
    if (idx >= total) return;
    const int r = idx / Kp, k = idx - r * Kp;
    out[idx] = (k < K) ? f2bf(in[(size_t)r * K + k]) : (ushort_t)0;
}

__global__ void sos_init_bf16(ushort_t* __restrict__ sos)
{
    const int i = blockIdx.x * 256 + threadIdx.x;
    if (i < 512 * 320) sos[i] = ((i % 320) == 0) ? (ushort_t)0x3F80 : (ushort_t)0;
}

__global__ void permute_bias(const float* __restrict__ b1,
                             const float* __restrict__ b2,
                             float* __restrict__ out)
{
    const int c = blockIdx.x * 256 + threadIdx.x;
    if (c >= 4096) return;
    const int g = (c >> 4) & 3;
    const int j = (c >> 6) * 16 + (c & 15);
    out[c] = b1[g * 1024 + j] + b2[g * 1024 + j];
}

// One block per row of logits [16384][384] (valid cols 0..257); row = t*512+b.
__global__ __launch_bounds__(256) void logsoftmax_kernel(
    const float* __restrict__ logits, float* __restrict__ out)
{
    const int row = blockIdx.x;
    const int tid = threadIdx.x;
    const float* L = logits + (size_t)row * 384;
    const int t = row >> 9;
    const int b = row & 511;
    float* O = out + ((size_t)b * 32 + t) * 258;

    const float x0 = L[tid];
    const float x1 = (tid < 2) ? L[256 + tid] : -1e30f;

    __shared__ float sm[4];
    float m = fmaxf(x0, x1);
#pragma unroll
    for (int off = 32; off > 0; off >>= 1) m = fmaxf(m, __shfl_down(m, off));
    if ((tid & 63) == 0) sm[tid >> 6] = m;
    __syncthreads();
    m = fmaxf(fmaxf(sm[0], sm[1]), fmaxf(sm[2], sm[3]));
    __syncthreads();

    float s = expf(x0 - m) + ((tid < 2) ? expf(x1 - m) : 0.f);
#pragma unroll
    for (int off = 32; off > 0; off >>= 1) s += __shfl_down(s, off);
    if ((tid & 63) == 0) sm[tid >> 6] = s;
    __syncthreads();
    s = sm[0] + sm[1] + sm[2] + sm[3];

    const float lse = m + logf(s);
    O[tid] = x0 - lse;
    if (tid < 2) O[256 + tid] = x1 - lse;
}

}  // namespace

extern "C" void kernel_launch(void* const* d_in, const int* in_sizes, int n_in,
                              void* d_out, int out_size, void* d_ws, size_t ws_size,
                              hipStream_t stream)
{
    (void)in_sizes; (void)n_in; (void)out_size; (void)ws_size;

    const float* z    = (const float*)d_in[0];
    const float* x    = (const float*)d_in[1];
    const float* cin  = (const float*)d_in[2];
    const float* ciW  = (const float*)d_in[3];
    const float* cib  = (const float*)d_in[4];
    const float* cW1i = (const float*)d_in[5];
    const float* cW1h = (const float*)d_in[6];
    const float* cb1i = (const float*)d_in[7];
    const float* cb1h = (const float*)d_in[8];
    const float* cW2i = (const float*)d_in[9];
    const float* cW2h = (const float*)d_in[10];
    const float* cb2i = (const float*)d_in[11];
    const float* cb2h = (const float*)d_in[12];
    const float* coW  = (const float*)d_in[13];
    const float* cob  = (const float*)d_in[14];
    const float* diW  = (const float*)d_in[15];
    const float* dib  = (const float*)d_in[16];
    const float* dW1i = (const float*)d_in[17];
    const float* dW1h = (const float*)d_in[18];
    const float* db1i = (const float*)d_in[19];
    const float* db1h = (const float*)d_in[20];
    const float* dW2i = (const float*)d_in[21];
    const float* dW2h = (const float*)d_in[22];
    const float* db2i = (const float*)d_in[23];
    const float* db2h = (const float*)d_in[24];
    const float* fcW  = (const float*)d_in[25];
    const float* fcb  = (const float*)d_in[26];
    float* out = (float*)d_out;

    // ---- workspace ----
    char* wsp = (char*)d_ws;
    size_t off = 0;
    auto allocf = [&](size_t n) { float* p = (float*)(wsp + off); off += n * 4; return p; };
    auto allocb = [&](size_t n) { ushort_t* p = (ushort_t*)(wsp + off); off += n * 2; return p; };

    float* cst = allocf((size_t)3 * 1024 * 1024 + 64);
    float* c1c = cst;
    float* c2c = cst + (size_t)512 * 1024;
    float* c1d = cst + (size_t)1024 * 1024;
    float* c2d = cst + (size_t)2 * 1024 * 1024;
    float* pb1c = allocf(4096);
    float* pb2c = allocf(4096);
    float* pb1d = allocf(4096);
    float* pb2d = allocf(4096);
    float* logits = allocf((size_t)16384 * 384);

    ushort_t* h2z  = allocb((size_t)2 * (512 + 1024) * 1024);
    ushort_t* hc2A = h2z;
    ushort_t* hc2B = h2z + (size_t)512 * 1024;
    ushort_t* h2dA = h2z + (size_t)2 * 512 * 1024;
    ushort_t* h2dB = h2z + (size_t)(2 * 512 + 1024) * 1024;

    ushort_t* hc1A = allocb((size_t)512 * 1024);
    ushort_t* hc1B = allocb((size_t)512 * 1024);
    ushort_t* h1dA = allocb((size_t)1024 * 1024);
    ushort_t* h1dB = allocb((size_t)1024 * 1024);

    ushort_t* zbf    = allocb((size_t)512 * 512);
    ushort_t* cinbf  = allocb((size_t)512 * 320);
    ushort_t* sosbf  = allocb((size_t)512 * 320);
    ushort_t* xbf    = allocb((size_t)16384 * 320);
    ushort_t* chbf   = allocb((size_t)1024 * 1024);
    ushort_t* ccode  = allocb((size_t)1024 * 512);
    ushort_t* cpre   = allocb((size_t)1024 * 4096);
    ushort_t* xW1c   = allocb((size_t)512 * 4096);
    ushort_t* hsbf   = allocb((size_t)16384 * 1024);

    // packed frag-major weights
    ushort_t* ciWp  = allocb((size_t)1024 * 512);
    ushort_t* cW1ip = allocb((size_t)4096 * 320);
    ushort_t* cW1hp = allocb((size_t)4096 * 1024);
    ushort_t* cW2ip = allocb((size_t)4096 * 1024);
    ushort_t* cW2hp = allocb((size_t)4096 * 1024);
    ushort_t* coWp  = allocb((size_t)512 * 1024);
    ushort_t* dtopp = allocb((size_t)4096 * 512);
    ushort_t* dbotp = allocb((size_t)4096 * 320);
    ushort_t* diWp  = allocb((size_t)1024 * 512);
    ushort_t* dW1hp = allocb((size_t)4096 * 1024);
    ushort_t* dW2ip = allocb((size_t)4096 * 1024);
    ushort_t* dW2hp = allocb((size_t)4096 * 1024);
    ushort_t* fcWp  = allocb((size_t)384 * 1024);

    hipMemsetAsync(cst, 0, (size_t)3 * 1024 * 1024 * 4, stream);
    hipMemsetAsync(h2z, 0, (size_t)2 * (512 + 1024) * 1024 * 2, stream);

    // ---- weight pack ----
    auto pack = [&](const float* in, ushort_t* o, int K, int N, int Kp, int Np, int perm) {
        dim3 g(Kp / 32, Np / 32);
        if (perm) pack_frag_bf16<1><<<g, 256, 0, stream>>>(in, o, K, N, Kp, Np);
        else      pack_frag_bf16<0><<<g, 256, 0, stream>>>(in, o, K, N, Kp, Np);
    };
    pack(ciW, ciWp, 512, 1024, 512, 1024, 0);
    pack(cW1i, cW1ip, 258, 4096, 320, 4096, 1);
    pack(cW1h, cW1hp, 1024, 4096, 1024, 4096, 1);
    pack(cW2i, cW2ip, 1024, 4096, 1024, 4096, 1);
    pack(cW2h, cW2hp, 1024, 4096, 1024, 4096, 1);
    pack(coW, coWp, 1024, 512, 1024, 512, 0);
    pack(dW1i, dtopp, 512, 4096, 512, 4096, 1);
    pack(dW1i + (size_t)512 * 4096, dbotp, 258, 4096, 320, 4096, 1);
    pack(diW, diWp, 512, 1024, 512, 1024, 0);
    pack(dW1h, dW1hp, 1024, 4096, 1024, 4096, 1);
    pack(dW2i, dW2ip, 1024, 4096, 1024, 4096, 1);
    pack(dW2h, dW2hp, 1024, 4096, 1024, 4096, 1);
    pack(fcW, fcWp, 1024, 258, 1024, 384, 0);

    auto convert = [&](const float* in, ushort_t* o, int K, int Kp, int R) {
        const int total = R * Kp;
        convert_pad_bf16<<<dim3((total + 255) / 256), 256, 0, stream>>>(in, o, K, Kp, total);
    };
    convert(z, zbf, 512, 512, 512);
    convert(cin, cinbf, 258, 320, 512);
    convert(x, xbf, 258, 320, 16384);
    sos_init_bf16<<<dim3((512 * 320 + 255) / 256), 256, 0, stream>>>(sosbf);
    permute_bias<<<16, 256, 0, stream>>>(cb1i, cb1h, pb1c);
    permute_bias<<<16, 256, 0, stream>>>(cb2i, cb2h, pb2c);
    permute_bias<<<16, 256, 0, stream>>>(db1i, db1h, pb1d);
    permute_bias<<<16, 256, 0, stream>>>(db2i, db2h, pb2d);

    auto gemm = [&](int act, const ushort_t* A, int lda, int K, const ushort_t* W,
                    const float* bias, int bias_n,
                    float* C, ushort_t* Cbf, int M, int N) {
        dim3 g(M / 64, N / 128);
        if (act) plain_gemm<1><<<g, 256, 0, stream>>>(A, lda, K, W, bias, bias_n, C, Cbf, N);
        else     plain_gemm<0><<<g, 256, 0, stream>>>(A, lda, K, W, bias, bias_n, C, Cbf, N);
    };

    // ---- conductor init ----
    gemm(1, zbf, 512, 512, ciWp, cib, 1024, nullptr, hc1A, 512, 1024);
    gemm(0, cinbf, 320, 320, cW1ip, pb1c, 4096, nullptr, xW1c, 512, 4096);

    // ---- conductor: 3 fused iterations (L1 at k=0,1; L2 at k=1,2) ----
    ushort_t* HC1[2] = {hc1A, hc1B};
    ushort_t* HC2[2] = {hc2A, hc2B};
    for (int k = 0; k <= 2; ++k) {
        Prob pa{}, pb{};
        int nxa = 0, nxb = 0;
        if (k < 2) {
            pa = {HC1[k & 1], nullptr, 1024, 1024, cW1hp,
                  nullptr, 0, 0, nullptr,
                  xW1c, nullptr, c1c, HC1[(k + 1) & 1], nullptr, -1};
            nxa = 8;
        }
        if (k >= 1) {
            pb = {HC1[k & 1], nullptr, 1024, 1024, cW2ip,
                  HC2[k & 1], 1024, 1024, cW2hp,
                  nullptr, pb2c, c2c, HC2[(k + 1) & 1],
                  chbf + (size_t)(k - 1) * 512 * 1024, -1};
            nxb = 8;
        }
        const int nmb = nxa + nxb;               // 8 or 16
        const int mshift = (nmb == 8) ? 3 : 4;
        lstm_step<<<dim3(nmb * 32), 256, 0, stream>>>(pa, nxa, pb, mshift);
    }

    // ---- codes + decoder init ----
    gemm(0, chbf, 1024, 1024, coWp, cob, 512, nullptr, ccode, 1024, 512);
    gemm(0, ccode, 512, 512, dtopp, pb1d, 4096, nullptr, cpre, 1024, 4096);
    gemm(1, ccode, 512, 512, diWp, dib, 1024, nullptr, h1dA, 1024, 1024);

    // ---- decoder: 17 fused iterations (L1 at k=0..15; L2 at k=1..16) ----
    ushort_t* H1[2] = {h1dA, h1dB};
    ushort_t* H2[2] = {h2dA, h2dB};
    for (int k = 0; k <= 16; ++k) {
        Prob pa{}, pb{};
        int nxa = 0, nxb = 0;
        if (k < 16) {
            const ushort_t* plo = (k == 0) ? sosbf : (xbf + (size_t)(k - 1) * 512 * 320);
            const ushort_t* phi = xbf + (size_t)(15 + k) * 512 * 320;
            pa = {plo, phi, 320, 320, dbotp,
                  H1[k & 1], 1024, 1024, dW1hp,
                  cpre, nullptr, c1d, H1[(k + 1) & 1], nullptr, -1};
            nxa = 16;
        }
        if (k >= 1) {
            pb = {H1[k & 1], nullptr, 1024, 1024, dW2ip,
                  H2[k & 1], 1024, 1024, dW2hp,
                  nullptr, pb2d, c2d, H2[(k + 1) & 1], hsbf, k - 1};
            nxb = 16;
        }
        const int nmb = nxa + nxb;               // 16 or 32
        const int mshift = (nmb == 16) ? 4 : 5;
        lstm_step<<<dim3(nmb * 32), 256, 0, stream>>>(pa, nxa, pb, mshift);
    }

    // ---- projection + log_softmax ----
    gemm(0, hsbf, 1024, 1024, fcWp, fcb, 258, logits, nullptr, 16384, 384);
    logsoftmax_kernel<<<dim3(16384), 256, 0, stream>>>(logits, out);
}

// Round 10
// 1222.999 us; speedup vs baseline: 3.6669x; 3.6669x over previous
//
#include <hip/hip_runtime.h>
#include <cstddef>
#include <cstdint>

// Round 9: r8's 4-blocks/CU concurrency experiment, de-spilled.
//  - amdgpu_waves_per_eu(4,4): pin 4 waves/EU -> 128 VGPR cap (r8: compiler
//    targeted 8 waves/EU at 64 VGPR and spilled 620MB of scratch).
//  - B register ring of 2 (loadB(t+2) refills just-consumed regs post-MFMA).
//  - Ledger: prologue B0,A0,B1,A1 (10 outstanding). iter t: vmcnt(5) retires
//    exactly B(t)+A(t); barrier; stageA(t+2); MFMA(bcur); loadB(t+2)->bcur.

namespace {

typedef short s8v __attribute__((ext_vector_type(8)));
typedef float f4v __attribute__((ext_vector_type(4)));
typedef unsigned short ushort_t;

__device__ inline unsigned short f2bf(float f) {
    union { float f; unsigned u; } v; v.f = f;
    unsigned r = v.u + 0x7fff + ((v.u >> 16) & 1);
    return (unsigned short)(r >> 16);
}
__device__ inline float bf2f(ushort_t u) {
    union { unsigned u; float f; } v; v.u = ((unsigned)u) << 16; return v.f;
}
__device__ inline float sigm_f(float x) { return 1.f / (1.f + __expf(-x)); }
__device__ inline float tanh_f(float x) {
    const float e = __expf(2.f * fabsf(x));
    return copysignf(1.f - 2.f / (e + 1.f), x);
}

#define GLOAD_LDS(gp, lp)                                              \
    __builtin_amdgcn_global_load_lds(                                  \
        (const __attribute__((address_space(1))) void*)(gp),           \
        (__attribute__((address_space(3))) void*)(lp), 16, 0, 0)

// ---------------------------------------------------------------------------
// GEMM core: 64x128 tile, BK=32, 4 waves (2x2, wave-tile 32x64), acc[2][4].
// A row-major bf16 [M][K] via LDS (4KB/tile, ring of 3, depth 2), 2-way-max
// chunk swizzle (phys chunk = logical ^ ((row>>1)&3), pre-swizzled source).
// B direct-to-register from fragment-major packed weights, ring of 2.
// ---------------------------------------------------------------------------
__device__ __forceinline__ void gemm_core(
    const ushort_t* __restrict__ A1a, const ushort_t* __restrict__ A1b,
    int lda1, int K1, const ushort_t* __restrict__ W1,
    const ushort_t* __restrict__ A2, int lda2, int K2,
    const ushort_t* __restrict__ W2,
    int bm, int bn, ushort_t* lds, f4v acc[2][4])
{
    const int tid = threadIdx.x;
    const int wid = tid >> 6;
    const int lane = tid & 63;
    const int wr = wid >> 1, wc = wid & 1;
    const int lrow = lane & 15, lkg = lane >> 4;

    const int n1 = K1 >> 5;
    const int n2 = (W2 != nullptr) ? (K2 >> 5) : 0;
    const int nt = n1 + n2;

    // ---- A staging: wave wid covers rows [wid*16, +16), lane -> row lane>>2,
    // chunk lane&3; source chunk pre-swizzled; LDS dest linear. ----
    const int srow = wid * 16 + (lane >> 2);
    const int ssrc = (((lane & 3) ^ ((srow >> 1) & 3)) << 3);  // elems

    auto arow = [&](const ushort_t* Aa, const ushort_t* Ab, int lda,
                    int r) -> const ushort_t* {
        return (Ab != nullptr && r >= 512) ? Ab + (size_t)(r - 512) * lda
                                           : Aa + (size_t)r * lda;
    };
    const ushort_t* pA1 = arow(A1a, A1b, lda1, bm + srow) + ssrc;
    const ushort_t* pA2 = nullptr;
    if (n2 > 0) pA2 = A2 + (size_t)(bm + srow) * lda2 + ssrc;

    auto stageA = [&](int idx, int buf) {
        const ushort_t* p;
        if (idx < n1) p = pA1 + (idx << 5);
        else          p = pA2 + ((idx - n1) << 5);
        GLOAD_LDS(p, lds + buf * 2048 + wid * 512);
    };

    // ---- B packed bases: wave's 4 fragments at nb0 = bn/16 + wc*4 ----
    const int nb0 = (bn >> 4) + wc * 4;
    const ushort_t* W1l = W1 + (size_t)nb0 * n1 * 512 + lane * 8;
    const ushort_t* W2l = (n2 > 0) ? (W2 + (size_t)nb0 * n2 * 512 + lane * 8) : nullptr;

    auto loadB = [&](int t, s8v (&b)[4]) {
        const ushort_t* base; int kb, KB;
        if (t < n1) { base = W1l; kb = t; KB = n1; }
        else        { base = W2l; kb = t - n1; KB = n2; }
#pragma unroll
        for (int n = 0; n < 4; ++n)
            b[n] = *(const s8v*)(base + ((size_t)(n * KB + kb) << 9));
    };

    // ---- A fragment read offsets (swizzled), loop-invariant ----
    int aoff[2];
#pragma unroll
    for (int m = 0; m < 2; ++m) {
        const int r = wr * 32 + m * 16 + lrow;
        aoff[m] = r * 32 + ((lkg ^ ((r >> 1) & 3)) << 3);
    }

    s8v b0[4], b1[4];
    loadB(0, b0);
    stageA(0, 0);
    loadB(1, b1);
    stageA(1, 1);

    int cbuf = 0, sbuf = 2;
    auto iter = [&](int t, s8v (&bcur)[4]) {
        if (t + 1 < nt) asm volatile("s_waitcnt vmcnt(5)" ::: "memory");
        else            asm volatile("s_waitcnt vmcnt(0)" ::: "memory");
        __builtin_amdgcn_s_barrier();
        __builtin_amdgcn_sched_barrier(0);
        if (t + 2 < nt) {
            stageA(t + 2, sbuf);
            sbuf = (sbuf == 2) ? 0 : sbuf + 1;
        }
        const ushort_t* L = lds + cbuf * 2048;
        s8v a[2];
#pragma unroll
        for (int m = 0; m < 2; ++m) a[m] = *(const s8v*)(L + aoff[m]);
        __builtin_amdgcn_s_setprio(1);
#pragma unroll
        for (int m = 0; m < 2; ++m)
#pragma unroll
            for (int n = 0; n < 4; ++n)
                acc[m][n] = __builtin_amdgcn_mfma_f32_16x16x32_bf16(
                    a[m], bcur[n], acc[m][n], 0, 0, 0);
        __builtin_amdgcn_s_setprio(0);
        if (t + 2 < nt) loadB(t + 2, bcur);  // refill just-consumed ring slot
        cbuf = (cbuf == 2) ? 0 : cbuf + 1;
    };

    int t = 0;
    while (true) {
        iter(t, b0); if (++t == nt) break;
        iter(t, b1); if (++t == nt) break;
    }
}

// ---------------------------------------------------------------------------
// Plain GEMM: C = act(A@W^T + bias). M%64==0, N%128==0, K%32==0.
// ---------------------------------------------------------------------------
template <int ACT>  // 0 none, 1 tanh
__global__ __launch_bounds__(256)
__attribute__((amdgpu_waves_per_eu(4, 4))) void plain_gemm(
    const ushort_t* __restrict__ A, int lda, int K,
    const ushort_t* __restrict__ W,
    const float* __restrict__ bias, int bias_n,
    float* __restrict__ C, ushort_t* __restrict__ Cbf, int N)
{
    __shared__ __align__(16) ushort_t lds[3 * 2048];
    const int bm = blockIdx.x * 64, bn = blockIdx.y * 128;
    f4v acc[2][4] = {};
    gemm_core(A, nullptr, lda, K, W, nullptr, 0, 0, nullptr, bm, bn, lds, acc);

    const int tid = threadIdx.x, wid = tid >> 6, lane = tid & 63;
    const int wr = wid >> 1, wc = wid & 1, lrow = lane & 15, lkg = lane >> 4;
#pragma unroll
    for (int m = 0; m < 2; ++m) {
        const int row0 = bm + wr * 32 + m * 16 + lkg * 4;
#pragma unroll
        for (int n = 0; n < 4; ++n) {
            const int col = bn + wc * 64 + n * 16 + lrow;
            const float bv = (bias != nullptr && col < bias_n) ? bias[col] : 0.f;
#pragma unroll
            for (int r = 0; r < 4; ++r) {
                float v = acc[m][n][r] + bv;
                if (ACT == 1) v = tanh_f(v);
                const size_t o = (size_t)(row0 + r) * N + col;
                if (C != nullptr) C[o] = v;
                if (Cbf != nullptr) Cbf[o] = f2bf(v);
            }
        }
    }
}

// ---------------------------------------------------------------------------
// Fused LSTM step. Weights gate-interleaved: col' = (j>>4)*64 + g*16 + (j&15).
// ---------------------------------------------------------------------------
struct Prob {
    const ushort_t* A1a; const ushort_t* A1b; int lda1; int K1;
    const ushort_t* B1t;   // packed frag-major
    const ushort_t* A2; int lda2; int K2; const ushort_t* B2t;  // packed
    const ushort_t* Dbf;   // bf16 [M][4096] pre-gates (incl. bias), or null
    const float* bias;     // fp32 [4096] permuted combined bias, or null
    float* cst;            // fp32 [M][1024] cell state (in/out)
    ushort_t* hout;        // bf16 [M][1024] new hidden
    ushort_t* hs;          // optional extra hidden dest
    int step_s;            // -1: identity; >=0: decoder hs mapping
};

__global__ __launch_bounds__(256)
__attribute__((amdgpu_waves_per_eu(4, 4))) void lstm_step(Prob PA, int nxa,
                                                          Prob PB, int mshift)
{
    __shared__ __align__(16) ushort_t lds[3 * 2048];
    const int nblk = gridDim.x;
    const int wg = blockIdx.x;
    const int swz = (wg & 7) * (nblk >> 3) + (wg >> 3);
    const int nmb = 1 << mshift;
    const int nb = swz >> mshift;
    const int mb = swz & (nmb - 1);

    const bool isA = mb < nxa;
    const Prob& P = isA ? PA : PB;
    const int bm = (isA ? mb : mb - nxa) * 64;
    const int bn = nb * 128;

    f4v acc[2][4] = {};
    gemm_core(P.A1a, P.A1b, P.lda1, P.K1, P.B1t,
              P.A2, P.lda2, P.K2, P.B2t, bm, bn, lds, acc);

    const int tid = threadIdx.x, wid = tid >> 6, lane = tid & 63;
    const int wr = wid >> 1, wc = wid & 1, lrow = lane & 15, lkg = lane >> 4;
    const int colbase = bn + wc * 64;           // 64-aligned
    const int jb = (colbase >> 6) * 16 + lrow;  // hidden-unit index

#pragma unroll
    for (int m = 0; m < 2; ++m) {
        const int row0 = bm + wr * 32 + m * 16 + lkg * 4;
#pragma unroll
        for (int r = 0; r < 4; ++r) {
            const int row = row0 + r;
            float g0 = acc[m][0][r], g1 = acc[m][1][r];
            float g2 = acc[m][2][r], g3 = acc[m][3][r];
            if (P.Dbf != nullptr) {
                const ushort_t* d = P.Dbf + (size_t)row * 4096 + colbase + lrow;
                g0 += bf2f(d[0]); g1 += bf2f(d[16]);
                g2 += bf2f(d[32]); g3 += bf2f(d[48]);
            }
            if (P.bias != nullptr) {
                const float* b = P.bias + colbase + lrow;
                g0 += b[0]; g1 += b[16]; g2 += b[32]; g3 += b[48];
            }
            const size_t ci = (size_t)row * 1024 + jb;
            const float cn = fmaf(sigm_f(g1), P.cst[ci], sigm_f(g0) * tanh_f(g2));
            const float hn = sigm_f(g3) * tanh_f(cn);
            P.cst[ci] = cn;
            const ushort_t hb = f2bf(hn);
            P.hout[ci] = hb;
            if (P.hs != nullptr) {
                size_t d;
                if (P.step_s >= 0) {
                    const int u = row >> 9, b = row & 511;
                    d = ((size_t)((u * 16 + P.step_s) * 512 + b) << 10) + jb;
                } else {
                    d = ci;
                }
                P.hs[d] = hb;
            }
        }
    }
}

// ---------------------------------------------------------------------------
// Weight pack: fp32 W[K][N] -> fragment-major bf16 (see round 6).
// ---------------------------------------------------------------------------
template <int PERM>
__global__ __launch_bounds__(256) void pack_frag_bf16(
    const float* __restrict__ in, ushort_t* __restrict__ out,
    int K, int N, int Kp, int Np)
{
    __shared__ float tile[32][33];
    const int kb = blockIdx.x;
    const int np0 = blockIdx.y * 32;
    const int k0 = kb * 32;
    const int tx = threadIdx.x & 31;
    const int ty = threadIdx.x >> 5;  // 0..7
#pragma unroll
    for (int q = 0; q < 4; ++q) {
        const int k = k0 + ty + 8 * q;
        const int np = np0 + tx;
        int n;
        if (PERM) n = ((np >> 4) & 3) * 1024 + (np >> 6) * 16 + (np & 15);
        else      n = np;
        tile[ty + 8 * q][tx] = (k < K && n < N) ? in[(size_t)k * N + n] : 0.f;
    }
    __syncthreads();
    const int t = threadIdx.x;
    const int rec = t >> 7;           // 0..1
    const int lane = (t >> 1) & 63;
    const int half = t & 1;
    const size_t grec = (size_t)(np0 / 16 + rec) * (Kp / 32) + kb;
    const int kl = (lane >> 4) * 8 + half * 4;
    const int nl = rec * 16 + (lane & 15);
    ushort4 v;
    v.x = f2bf(tile[kl + 0][nl]);
    v.y = f2bf(tile[kl + 1][nl]);
    v.z = f2bf(tile[kl + 2][nl]);
    v.w = f2bf(tile[kl + 3][nl]);
    *(ushort4*)(out + (grec * 64 + lane) * 8 + half * 4) = v;
}

__global__ void convert_pad_bf16(const float* __restrict__ in,
                                 ushort_t* __restrict__ out,
                                 int K, int Kp, int total)
{
    const int idx = blockIdx.x * 256 + threadIdx.x;
    if (idx >= total) return;
    const int r = idx / Kp, k = idx - r * Kp;
    out[idx] = (k < K) ? f2bf(in[(size_t)r * K + k]) : (ushort_t)0;
}

__global__ void sos_init_bf16(ushort_t* __restrict__ sos)
{
    const int i = blockIdx.x * 256 + threadIdx.x;
    if (i < 512 * 320) sos[i] = ((i % 320) == 0) ? (ushort_t)0x3F80 : (ushort_t)0;
}

__global__ void permute_bias(const float* __restrict__ b1,
                             const float* __restrict__ b2,
                             float* __restrict__ out)
{
    const int c = blockIdx.x * 256 + threadIdx.x;
    if (c >= 4096) return;
    const int g = (c >> 4) & 3;
    const int j = (c >> 6) * 16 + (c & 15);
    out[c] = b1[g * 1024 + j] + b2[g * 1024 + j];
}

// One block per row of logits [16384][384] (valid cols 0..257); row = t*512+b.
__global__ __launch_bounds__(256) void logsoftmax_kernel(
    const float* __restrict__ logits, float* __restrict__ out)
{
    const int row = blockIdx.x;
    const int tid = threadIdx.x;
    const float* L = logits + (size_t)row * 384;
    const int t = row >> 9;
    const int b = row & 511;
    float* O = out + ((size_t)b * 32 + t) * 258;

    const float x0 = L[tid];
    const float x1 = (tid < 2) ? L[256 + tid] : -1e30f;

    __shared__ float sm[4];
    float m = fmaxf(x0, x1);
#pragma unroll
    for (int off = 32; off > 0; off >>= 1) m = fmaxf(m, __shfl_down(m, off));
    if ((tid & 63) == 0) sm[tid >> 6] = m;
    __syncthreads();
    m = fmaxf(fmaxf(sm[0], sm[1]), fmaxf(sm[2], sm[3]));
    __syncthreads();

    float s = expf(x0 - m) + ((tid < 2) ? expf(x1 - m) : 0.f);
#pragma unroll
    for (int off = 32; off > 0; off >>= 1) s += __shfl_down(s, off);
    if ((tid & 63) == 0) sm[tid >> 6] = s;
    __syncthreads();
    s = sm[0] + sm[1] + sm[2] + sm[3];

    const float lse = m + logf(s);
    O[tid] = x0 - lse;
    if (tid < 2) O[256 + tid] = x1 - lse;
}

}  // namespace

extern "C" void kernel_launch(void* const* d_in, const int* in_sizes, int n_in,
                              void* d_out, int out_size, void* d_ws, size_t ws_size,
                              hipStream_t stream)
{
    (void)in_sizes; (void)n_in; (void)out_size; (void)ws_size;

    const float* z    = (const float*)d_in[0];
    const float* x    = (const float*)d_in[1];
    const float* cin  = (const float*)d_in[2];
    const float* ciW  = (const float*)d_in[3];
    const float* cib  = (const float*)d_in[4];
    const float* cW1i = (const float*)d_in[5];
    const float* cW1h = (const float*)d_in[6];
    const float* cb1i = (const float*)d_in[7];
    const float* cb1h = (const float*)d_in[8];
    const float* cW2i = (const float*)d_in[9];
    const float* cW2h = (const float*)d_in[10];
    const float* cb2i = (const float*)d_in[11];
    const float* cb2h = (const float*)d_in[12];
    const float* coW  = (const float*)d_in[13];
    const float* cob  = (const float*)d_in[14];
    const float* diW  = (const float*)d_in[15];
    const float* dib  = (const float*)d_in[16];
    const float* dW1i = (const float*)d_in[17];
    const float* dW1h = (const float*)d_in[18];
    const float* db1i = (const float*)d_in[19];
    const float* db1h = (const float*)d_in[20];
    const float* dW2i = (const float*)d_in[21];
    const float* dW2h = (const float*)d_in[22];
    const float* db2i = (const float*)d_in[23];
    const float* db2h = (const float*)d_in[24];
    const float* fcW  = (const float*)d_in[25];
    const float* fcb  = (const float*)d_in[26];
    float* out = (float*)d_out;

    // ---- workspace ----
    char* wsp = (char*)d_ws;
    size_t off = 0;
    auto allocf = [&](size_t n) { float* p = (float*)(wsp + off); off += n * 4; return p; };
    auto allocb = [&](size_t n) { ushort_t* p = (ushort_t*)(wsp + off); off += n * 2; return p; };

    float* cst = allocf((size_t)3 * 1024 * 1024 + 64);
    float* c1c = cst;
    float* c2c = cst + (size_t)512 * 1024;
    float* c1d = cst + (size_t)1024 * 1024;
    float* c2d = cst + (size_t)2 * 1024 * 1024;
    float* pb1c = allocf(4096);
    float* pb2c = allocf(4096);
    float* pb1d = allocf(4096);
    float* pb2d = allocf(4096);
    float* logits = allocf((size_t)16384 * 384);

    ushort_t* h2z  = allocb((size_t)2 * (512 + 1024) * 1024);
    ushort_t* hc2A = h2z;
    ushort_t* hc2B = h2z + (size_t)512 * 1024;
    ushort_t* h2dA = h2z + (size_t)2 * 512 * 1024;
    ushort_t* h2dB = h2z + (size_t)(2 * 512 + 1024) * 1024;

    ushort_t* hc1A = allocb((size_t)512 * 1024);
    ushort_t* hc1B = allocb((size_t)512 * 1024);
    ushort_t* h1dA = allocb((size_t)1024 * 1024);
    ushort_t* h1dB = allocb((size_t)1024 * 1024);

    ushort_t* zbf    = allocb((size_t)512 * 512);
    ushort_t* cinbf  = allocb((size_t)512 * 320);
    ushort_t* sosbf  = allocb((size_t)512 * 320);
    ushort_t* xbf    = allocb((size_t)16384 * 320);
    ushort_t* chbf   = allocb((size_t)1024 * 1024);
    ushort_t* ccode  = allocb((size_t)1024 * 512);
    ushort_t* cpre   = allocb((size_t)1024 * 4096);
    ushort_t* xW1c   = allocb((size_t)512 * 4096);
    ushort_t* hsbf   = allocb((size_t)16384 * 1024);

    // packed frag-major weights
    ushort_t* ciWp  = allocb((size_t)1024 * 512);
    ushort_t* cW1ip = allocb((size_t)4096 * 320);
    ushort_t* cW1hp = allocb((size_t)4096 * 1024);
    ushort_t* cW2ip = allocb((size_t)4096 * 1024);
    ushort_t* cW2hp = allocb((size_t)4096 * 1024);
    ushort_t* coWp  = allocb((size_t)512 * 1024);
    ushort_t* dtopp = allocb((size_t)4096 * 512);
    ushort_t* dbotp = allocb((size_t)4096 * 320);
    ushort_t* diWp  = allocb((size_t)1024 * 512);
    ushort_t* dW1hp = allocb((size_t)4096 * 1024);
    ushort_t* dW2ip = allocb((size_t)4096 * 1024);
    ushort_t* dW2hp = allocb((size_t)4096 * 1024);
    ushort_t* fcWp  = allocb((size_t)384 * 1024);

    hipMemsetAsync(cst, 0, (size_t)3 * 1024 * 1024 * 4, stream);
    hipMemsetAsync(h2z, 0, (size_t)2 * (512 + 1024) * 1024 * 2, stream);

    // ---- weight pack ----
    auto pack = [&](const float* in, ushort_t* o, int K, int N, int Kp, int Np, int perm) {
        dim3 g(Kp / 32, Np / 32);
        if (perm) pack_frag_bf16<1><<<g, 256, 0, stream>>>(in, o, K, N, Kp, Np);
        else      pack_frag_bf16<0><<<g, 256, 0, stream>>>(in, o, K, N, Kp, Np);
    };
    pack(ciW, ciWp, 512, 1024, 512, 1024, 0);
    pack(cW1i, cW1ip, 258, 4096, 320, 4096, 1);
    pack(cW1h, cW1hp, 1024, 4096, 1024, 4096, 1);
    pack(cW2i, cW2ip, 1024, 4096, 1024, 4096, 1);
    pack(cW2h, cW2hp, 1024, 4096, 1024, 4096, 1);
    pack(coW, coWp, 1024, 512, 1024, 512, 0);
    pack(dW1i, dtopp, 512, 4096, 512, 4096, 1);
    pack(dW1i + (size_t)512 * 4096, dbotp, 258, 4096, 320, 4096, 1);
    pack(diW, diWp, 512, 1024, 512, 1024, 0);
    pack(dW1h, dW1hp, 1024, 4096, 1024, 4096, 1);
    pack(dW2i, dW2ip, 1024, 4096, 1024, 4096, 1);
    pack(dW2h, dW2hp, 1024, 4096, 1024, 4096, 1);
    pack(fcW, fcWp, 1024, 258, 1024, 384, 0);

    auto convert = [&](const float* in, ushort_t* o, int K, int Kp, int R) {
        const int total = R * Kp;
        convert_pad_bf16<<<dim3((total + 255) / 256), 256, 0, stream>>>(in, o, K, Kp, total);
    };
    convert(z, zbf, 512, 512, 512);
    convert(cin, cinbf, 258, 320, 512);
    convert(x, xbf, 258, 320, 16384);
    sos_init_bf16<<<dim3((512 * 320 + 255) / 256), 256, 0, stream>>>(sosbf);
    permute_bias<<<16, 256, 0, stream>>>(cb1i, cb1h, pb1c);
    permute_bias<<<16, 256, 0, stream>>>(cb2i, cb2h, pb2c);
    permute_bias<<<16, 256, 0, stream>>>(db1i, db1h, pb1d);
    permute_bias<<<16, 256, 0, stream>>>(db2i, db2h, pb2d);

    auto gemm = [&](int act, const ushort_t* A, int lda, int K, const ushort_t* W,
                    const float* bias, int bias_n,
                    float* C, ushort_t* Cbf, int M, int N) {
        dim3 g(M / 64, N / 128);
        if (act) plain_gemm<1><<<g, 256, 0, stream>>>(A, lda, K, W, bias, bias_n, C, Cbf, N);
        else     plain_gemm<0><<<g, 256, 0, stream>>>(A, lda, K, W, bias, bias_n, C, Cbf, N);
    };

    // ---- conductor init ----
    gemm(1, zbf, 512, 512, ciWp, cib, 1024, nullptr, hc1A, 512, 1024);
    gemm(0, cinbf, 320, 320, cW1ip, pb1c, 4096, nullptr, xW1c, 512, 4096);

    // ---- conductor: 3 fused iterations (L1 at k=0,1; L2 at k=1,2) ----
    ushort_t* HC1[2] = {hc1A, hc1B};
    ushort_t* HC2[2] = {hc2A, hc2B};
    for (int k = 0; k <= 2; ++k) {
        Prob pa{}, pb{};
        int nxa = 0, nxb = 0;
        if (k < 2) {
            pa = {HC1[k & 1], nullptr, 1024, 1024, cW1hp,
                  nullptr, 0, 0, nullptr,
                  xW1c, nullptr, c1c, HC1[(k + 1) & 1], nullptr, -1};
            nxa = 8;
        }
        if (k >= 1) {
            pb = {HC1[k & 1], nullptr, 1024, 1024, cW2ip,
                  HC2[k & 1], 1024, 1024, cW2hp,
                  nullptr, pb2c, c2c, HC2[(k + 1) & 1],
                  chbf + (size_t)(k - 1) * 512 * 1024, -1};
            nxb = 8;
        }
        const int nmb = nxa + nxb;               // 8 or 16
        const int mshift = (nmb == 8) ? 3 : 4;
        lstm_step<<<dim3(nmb * 32), 256, 0, stream>>>(pa, nxa, pb, mshift);
    }

    // ---- codes + decoder init ----
    gemm(0, chbf, 1024, 1024, coWp, cob, 512, nullptr, ccode, 1024, 512);
    gemm(0, ccode, 512, 512, dtopp, pb1d, 4096, nullptr, cpre, 1024, 4096);
    gemm(1, ccode, 512, 512, diWp, dib, 1024, nullptr, h1dA, 1024, 1024);

    // ---- decoder: 17 fused iterations (L1 at k=0..15; L2 at k=1..16) ----
    ushort_t* H1[2] = {h1dA, h1dB};
    ushort_t* H2[2] = {h2dA, h2dB};
    for (int k = 0; k <= 16; ++k) {
        Prob pa{}, pb{};
        int nxa = 0, nxb = 0;
        if (k < 16) {
            const ushort_t* plo = (k == 0) ? sosbf : (xbf + (size_t)(k - 1) * 512 * 320);
            const ushort_t* phi = xbf + (size_t)(15 + k) * 512 * 320;
            pa = {plo, phi, 320, 320, dbotp,
                  H1[k & 1], 1024, 1024, dW1hp,
                  cpre, nullptr, c1d, H1[(k + 1) & 1], nullptr, -1};
            nxa = 16;
        }
        if (k >= 1) {
            pb = {H1[k & 1], nullptr, 1024, 1024, dW2ip,
                  H2[k & 1], 1024, 1024, dW2hp,
                  nullptr, pb2d, c2d, H2[(k + 1) & 1], hsbf, k - 1};
            nxb = 16;
        }
        const int nmb = nxa + nxb;               // 16 or 32
        const int mshift = (nmb == 16) ? 4 : 5;
        lstm_step<<<dim3(nmb * 32), 256, 0, stream>>>(pa, nxa, pb, mshift);
    }

    // ---- projection + log_softmax ----
    gemm(0, hsbf, 1024, 1024, fcWp, fcb, 258, logits, nullptr, 16384, 384);
    logsoftmax_kernel<<<dim3(16384), 256, 0, stream>>>(logits, out);
}